// Round 1
// baseline (139.463 us; speedup 1.0000x reference)
//
#include <hip/hip_runtime.h>
#include <hip/hip_bf16.h>

// CategorySpecificLinear: out[b,t,h] = sum_d x[b,t,d] * W[cat[b],d,h] + bias[cat[b],h]
// B=256, T=32, D=1024, H=1024, NCAT=32.
// Strategy: group batches by category (setup kernel builds <=96 tile records of
// up to 4 batches = 128 rows), then grouped bf16-MFMA GEMM, fp32 accumulate.

#define NCAT 32
#define DIN  1024
#define DH   1024
#define NBATCH 256
#define TT   32
#define MAXREC 96

#define BM 128
#define BN 128
#define BK 32
#define LDK 40   // LDS row stride in bf16 elems (BK + 8 pad): 80B, 16B-aligned, conflict-light

typedef __attribute__((ext_vector_type(4))) float f32x4;
typedef __attribute__((ext_vector_type(8))) short bf16x8;
typedef __attribute__((ext_vector_type(4))) short bf16x4;

__device__ inline short f2bf(float f) {
    // round-to-nearest-even fp32 -> bf16
    unsigned u = __builtin_bit_cast(unsigned, f);
    u += 0x7fffu + ((u >> 16) & 1u);
    return (short)(u >> 16);
}

// ---------------------------------------------------------------------------
// Setup: build tile records {cat, nb, b0,b1,b2,b3, pad, pad} (8 ints each).
// Each record covers up to 4 batches of the same category (BM=128 rows).
// max records = sum ceil(cnt_c/4) <= (256 + 32*3)/4 = 88 <= 96.
// ---------------------------------------------------------------------------
__global__ void cat_setup_kernel(const int* __restrict__ cat_ids,
                                 int* __restrict__ recs) {
    __shared__ int cats[NBATCH];
    __shared__ int offs[NCAT + 1];
    const int t = threadIdx.x;
    cats[t] = cat_ids[t];
    for (int i = t; i < MAXREC * 8; i += 256) recs[i] = 0;
    __syncthreads();
    if (t < NCAT) {
        int cnt = 0;
        for (int i = 0; i < NBATCH; ++i) cnt += (cats[i] == t) ? 1 : 0;
        offs[t + 1] = (cnt + 3) >> 2;
    }
    __syncthreads();
    if (t == 0) {
        offs[0] = 0;
        for (int c = 0; c < NCAT; ++c) offs[c + 1] += offs[c];
    }
    __syncthreads();
    if (t < NCAT) {
        int base = offs[t];
        int buf0 = 0, buf1 = 0, buf2 = 0, buf3 = 0;
        int nb = 0, k = 0;
        for (int i = 0; i < NBATCH; ++i) {
            if (cats[i] == t) {
                if (nb == 0) buf0 = i; else if (nb == 1) buf1 = i;
                else if (nb == 2) buf2 = i; else buf3 = i;
                ++nb;
                if (nb == 4) {
                    int* r = recs + (base + k) * 8;
                    r[0] = t; r[1] = 4;
                    r[2] = buf0; r[3] = buf1; r[4] = buf2; r[5] = buf3;
                    ++k; nb = 0;
                }
            }
        }
        if (nb > 0) {
            int* r = recs + (base + k) * 8;
            r[0] = t; r[1] = nb;
            r[2] = buf0;
            r[3] = (nb > 1) ? buf1 : buf0;
            r[4] = (nb > 2) ? buf2 : buf0;
            r[5] = (nb > 3) ? buf3 : buf0;
        }
    }
}

// ---------------------------------------------------------------------------
// Grouped GEMM: one block = one (record, n-tile). 256 threads = 4 waves (2x2),
// wave tile 64x64, mfma_f32_16x16x32_bf16.
// ---------------------------------------------------------------------------
__launch_bounds__(256, 2)
__global__ void cat_gemm_kernel(const float* __restrict__ x,
                                const float* __restrict__ W,
                                const float* __restrict__ bias,
                                const int* __restrict__ recs,
                                float* __restrict__ out) {
    const int* rec = recs + blockIdx.y * 8;
    const int cat = rec[0];
    const int nb  = rec[1];
    if (nb == 0) return;
    const int n0 = blockIdx.x * BN;

    __shared__ short xs[BM * LDK];
    __shared__ short wt[BN * LDK];

    const int t    = threadIdx.x;
    const int lane = t & 63;
    const int wid  = t >> 6;
    const int wm   = wid >> 1;   // wave row 0..1
    const int wn   = wid & 1;    // wave col 0..1
    const int fl   = lane & 15;
    const int kb   = lane >> 4;  // k-block of 8 within BK=32

    // --- X staging: thread -> tile row xr = t>>1, 16 cols at xc0 ---
    const int xr    = t >> 1;
    const int xc0   = (t & 1) * 16;
    const int xbatch = rec[2 + (xr >> 5)];
    const float* xsrc = x + (size_t)(xbatch * TT + (xr & 31)) * DIN + xc0;
    short* xdst = xs + xr * LDK + xc0;

    // --- W staging: thread -> k rows wk4..wk4+3 (k fast across lanes for
    //     conflict-free transpose writes), n cols wn4..wn4+3 ---
    const int wk4 = (t & 7) * 4;
    const int wn4 = (t >> 3) * 4;
    const float* wsrc = W + (size_t)cat * (DIN * DH) + (size_t)wk4 * DH + n0 + wn4;

    f32x4 acc[4][4];
#pragma unroll
    for (int i = 0; i < 4; ++i)
#pragma unroll
        for (int j = 0; j < 4; ++j)
            acc[i][j] = (f32x4){0.f, 0.f, 0.f, 0.f};

    const short* aptr = xs + (wm * 64 + fl) * LDK + kb * 8;
    const short* bptr = wt + (wn * 64 + fl) * LDK + kb * 8;

    for (int k0 = 0; k0 < DIN; k0 += BK) {
        // global loads (fp32)
        f32x4 xv[4], wv[4];
#pragma unroll
        for (int i = 0; i < 4; ++i)
            xv[i] = *(const f32x4*)(xsrc + k0 + i * 4);
#pragma unroll
        for (int i = 0; i < 4; ++i)
            wv[i] = *(const f32x4*)(wsrc + (size_t)(k0 + i) * DH);

        // X: convert 16 fp32 -> 16 bf16, two 16B LDS writes
        bf16x8 p0, p1;
#pragma unroll
        for (int i = 0; i < 4; ++i) {
            p0[i]     = f2bf(xv[0][i]);
            p0[i + 4] = f2bf(xv[1][i]);
            p1[i]     = f2bf(xv[2][i]);
            p1[i + 4] = f2bf(xv[3][i]);
        }
        *(bf16x8*)(xdst)     = p0;
        *(bf16x8*)(xdst + 8) = p1;

        // W: 4x4 register transpose, write k-contiguous b64s: wt[n][k]
#pragma unroll
        for (int j = 0; j < 4; ++j) {
            bf16x4 q;
            q[0] = f2bf(wv[0][j]);
            q[1] = f2bf(wv[1][j]);
            q[2] = f2bf(wv[2][j]);
            q[3] = f2bf(wv[3][j]);
            *(bf16x4*)(wt + (wn4 + j) * LDK + wk4) = q;
        }

        __syncthreads();

        bf16x8 af[4], bfr[4];
#pragma unroll
        for (int mi = 0; mi < 4; ++mi)
            af[mi] = *(const bf16x8*)(aptr + mi * 16 * LDK);
#pragma unroll
        for (int ni = 0; ni < 4; ++ni)
            bfr[ni] = *(const bf16x8*)(bptr + ni * 16 * LDK);

#pragma unroll
        for (int mi = 0; mi < 4; ++mi)
#pragma unroll
            for (int ni = 0; ni < 4; ++ni)
                acc[mi][ni] = __builtin_amdgcn_mfma_f32_16x16x32_bf16(
                    af[mi], bfr[ni], acc[mi][ni], 0, 0, 0);

        __syncthreads();
    }

    // --- epilogue: bias + store (only rows of real batches) ---
    float bv[4];
#pragma unroll
    for (int ni = 0; ni < 4; ++ni)
        bv[ni] = bias[cat * DH + n0 + wn * 64 + ni * 16 + fl];

#pragma unroll
    for (int mi = 0; mi < 4; ++mi) {
        const int slot = wm * 2 + (mi >> 1);   // compile-time per unrolled mi
        if (slot < nb) {
            const int batch = rec[2 + slot];
            const int rbase = wm * 64 + mi * 16 + kb * 4;
#pragma unroll
            for (int j = 0; j < 4; ++j) {
                const int trow = (rbase + j) & 31;
                float* orow = out + (size_t)(batch * TT + trow) * DH + n0 + wn * 64;
#pragma unroll
                for (int ni = 0; ni < 4; ++ni)
                    orow[ni * 16 + fl] = acc[mi][ni][j] + bv[ni];
            }
        }
    }
}

extern "C" void kernel_launch(void* const* d_in, const int* in_sizes, int n_in,
                              void* d_out, int out_size, void* d_ws, size_t ws_size,
                              hipStream_t stream) {
    const float* x       = (const float*)d_in[0];
    const int*   cat_ids = (const int*)d_in[1];
    const float* W       = (const float*)d_in[2];
    const float* bias    = (const float*)d_in[3];
    float*       out     = (float*)d_out;
    int*         recs    = (int*)d_ws;

    hipLaunchKernelGGL(cat_setup_kernel, dim3(1), dim3(256), 0, stream,
                       cat_ids, recs);
    hipLaunchKernelGGL(cat_gemm_kernel, dim3(DH / BN, MAXREC), dim3(256), 0, stream,
                       x, W, bias, recs, out);
}

// Round 2
// 128.331 us; speedup vs baseline: 1.0867x; 1.0867x over previous
//
#include <hip/hip_runtime.h>
#include <hip/hip_bf16.h>

// CategorySpecificLinear: out[b,t,h] = sum_d x[b,t,d] * W[cat[b],d,h] + bias[cat[b],h]
// B=256, T=32, D=1024, H=1024, NCAT=32.
// R2: grouped bf16-MFMA GEMM with 2-deep register prefetch + double-buffered LDS,
// raw s_barrier (lgkmcnt-only drain) so prefetch loads stay in flight across the
// barrier; XCD-chunked block swizzle for L2 reuse.

#define NCAT 32
#define DIN  1024
#define DH   1024
#define NBATCH 256
#define TT   32
#define MAXREC 96

#define BM 128
#define BN 128
#define BK 32
#define LDK 40   // LDS row stride in bf16 elems (BK + 8 pad)
#define NITER (DIN / BK)
#define NTILES (DH / BN)   // 8

typedef __attribute__((ext_vector_type(4))) float f32x4;
typedef __attribute__((ext_vector_type(8))) short bf16x8;
typedef __attribute__((ext_vector_type(4))) short bf16x4;

__device__ inline short f2bf(float f) {
    unsigned u = __builtin_bit_cast(unsigned, f);
    u += 0x7fffu + ((u >> 16) & 1u);
    return (short)(u >> 16);
}

// ---------------------------------------------------------------------------
// Setup: bucket batches by category into <=96 records {cat, nb, b0..b3, pad2}.
// ---------------------------------------------------------------------------
__global__ void cat_setup_kernel(const int* __restrict__ cat_ids,
                                 int* __restrict__ recs) {
    __shared__ int cats[NBATCH];
    __shared__ int offs[NCAT + 1];
    const int t = threadIdx.x;
    cats[t] = cat_ids[t];
    for (int i = t; i < MAXREC * 8; i += 256) recs[i] = 0;
    __syncthreads();
    if (t < NCAT) {
        int cnt = 0;
        for (int i = 0; i < NBATCH; ++i) cnt += (cats[i] == t) ? 1 : 0;
        offs[t + 1] = (cnt + 3) >> 2;
    }
    __syncthreads();
    if (t == 0) {
        offs[0] = 0;
        for (int c = 0; c < NCAT; ++c) offs[c + 1] += offs[c];
    }
    __syncthreads();
    if (t < NCAT) {
        int base = offs[t];
        int b0 = 0, b1 = 0, b2 = 0, b3 = 0;
        int nb = 0, k = 0;
        for (int i = 0; i < NBATCH; ++i) {
            if (cats[i] == t) {
                if (nb == 0) b0 = i; else if (nb == 1) b1 = i;
                else if (nb == 2) b2 = i; else b3 = i;
                ++nb;
                if (nb == 4) {
                    int* r = recs + (base + k) * 8;
                    r[0] = t; r[1] = 4; r[2] = b0; r[3] = b1; r[4] = b2; r[5] = b3;
                    ++k; nb = 0;
                }
            }
        }
        if (nb > 0) {
            int* r = recs + (base + k) * 8;
            r[0] = t; r[1] = nb;
            r[2] = b0;
            r[3] = (nb > 1) ? b1 : b0;
            r[4] = (nb > 2) ? b2 : b0;
            r[5] = (nb > 3) ? b3 : b0;
        }
    }
}

// ---------------------------------------------------------------------------
// Grouped GEMM, pipelined. 256 threads = 4 waves (2x2), wave tile 64x64.
// ---------------------------------------------------------------------------
__launch_bounds__(256, 2)
__global__ void cat_gemm_kernel(const float* __restrict__ x,
                                const float* __restrict__ W,
                                const float* __restrict__ bias,
                                const int* __restrict__ recs,
                                float* __restrict__ out) {
    // XCD-chunked swizzle: 768 blocks = 8 XCDs x 96; consecutive lin on one XCD
    // walk n-tiles within a record, then consecutive (same-cat) records.
    const int wg    = blockIdx.x;
    const int lin   = (wg & 7) * ((MAXREC * NTILES) / 8) + (wg >> 3);
    const int irec  = lin >> 3;
    const int ntile = lin & 7;

    const int* rec = recs + irec * 8;
    const int cat = rec[0];
    const int nb  = rec[1];
    if (nb == 0) return;
    const int n0 = ntile * BN;

    __shared__ short xs[2][BM * LDK];
    __shared__ short wt[2][BN * LDK];

    const int t    = threadIdx.x;
    const int lane = t & 63;
    const int wid  = t >> 6;
    const int wm   = wid >> 1;
    const int wn   = wid & 1;
    const int fl   = lane & 15;
    const int kb   = lane >> 4;

    // X staging: row xr = t>>1, 16 cols at xc0
    const int xr     = t >> 1;
    const int xc0    = (t & 1) * 16;
    const int xbatch = rec[2 + (xr >> 5)];
    const float* xsrc = x + (size_t)(xbatch * TT + (xr & 31)) * DIN + xc0;
    short* xdst0 = &xs[0][0] + xr * LDK + xc0;
    short* xdst1 = &xs[1][0] + xr * LDK + xc0;

    // W staging: k rows wk4..wk4+3, n cols wn4..wn4+3 (register 4x4 transpose)
    const int wk4 = (t & 7) * 4;
    const int wn4 = (t >> 3) * 4;
    const float* wsrc = W + (size_t)cat * (DIN * DH) + (size_t)wk4 * DH + n0 + wn4;

    // bias early (latency hidden under K loop)
    float bv[4];
#pragma unroll
    for (int ni = 0; ni < 4; ++ni)
        bv[ni] = bias[cat * DH + n0 + wn * 64 + ni * 16 + fl];

    f32x4 acc[4][4];
#pragma unroll
    for (int i = 0; i < 4; ++i)
#pragma unroll
        for (int j = 0; j < 4; ++j)
            acc[i][j] = (f32x4){0.f, 0.f, 0.f, 0.f};

    const short* ap0 = &xs[0][0] + (wm * 64 + fl) * LDK + kb * 8;
    const short* ap1 = &xs[1][0] + (wm * 64 + fl) * LDK + kb * 8;
    const short* bp0 = &wt[0][0] + (wn * 64 + fl) * LDK + kb * 8;
    const short* bp1 = &wt[1][0] + (wn * 64 + fl) * LDK + kb * 8;

    // prologue: load K-tile 0 into registers
    f32x4 xv[4], wv[4];
#pragma unroll
    for (int i = 0; i < 4; ++i) xv[i] = *(const f32x4*)(xsrc + i * 4);
#pragma unroll
    for (int i = 0; i < 4; ++i) wv[i] = *(const f32x4*)(wsrc + (size_t)i * DH);

    for (int it = 0; it < NITER; ++it) {
        const int buf = it & 1;

        // --- convert + LDS write of tile `it` (waits on its loads via reg dep) ---
        short* xd = buf ? xdst1 : xdst0;
        bf16x8 p0, p1;
#pragma unroll
        for (int i = 0; i < 4; ++i) {
            p0[i]     = f2bf(xv[0][i]);
            p0[i + 4] = f2bf(xv[1][i]);
            p1[i]     = f2bf(xv[2][i]);
            p1[i + 4] = f2bf(xv[3][i]);
        }
        *(bf16x8*)(xd)     = p0;
        *(bf16x8*)(xd + 8) = p1;

        short* wdb = buf ? &wt[1][0] : &wt[0][0];
#pragma unroll
        for (int j = 0; j < 4; ++j) {
            bf16x4 q;
            q[0] = f2bf(wv[0][j]);
            q[1] = f2bf(wv[1][j]);
            q[2] = f2bf(wv[2][j]);
            q[3] = f2bf(wv[3][j]);
            *(bf16x4*)(wdb + (wn4 + j) * LDK + wk4) = q;
        }

        // --- issue prefetch for tile it+1 (rides across the barrier) ---
        if (it + 1 < NITER) {
            const int k0 = (it + 1) * BK;
#pragma unroll
            for (int i = 0; i < 4; ++i)
                xv[i] = *(const f32x4*)(xsrc + k0 + i * 4);
#pragma unroll
            for (int i = 0; i < 4; ++i)
                wv[i] = *(const f32x4*)(wsrc + (size_t)(k0 + i) * DH);
        }

        // drain LDS writes only — NOT vmcnt (prefetch stays in flight)
        asm volatile("s_waitcnt lgkmcnt(0)" ::: "memory");
        __builtin_amdgcn_s_barrier();
        asm volatile("" ::: "memory");

        // --- fragments + MFMA on tile `it` ---
        const short* ap = buf ? ap1 : ap0;
        const short* bp = buf ? bp1 : bp0;
        bf16x8 af[4], bfr[4];
#pragma unroll
        for (int mi = 0; mi < 4; ++mi)
            af[mi] = *(const bf16x8*)(ap + mi * 16 * LDK);
#pragma unroll
        for (int ni = 0; ni < 4; ++ni)
            bfr[ni] = *(const bf16x8*)(bp + ni * 16 * LDK);

#pragma unroll
        for (int mi = 0; mi < 4; ++mi)
#pragma unroll
            for (int ni = 0; ni < 4; ++ni)
                acc[mi][ni] = __builtin_amdgcn_mfma_f32_16x16x32_bf16(
                    af[mi], bfr[ni], acc[mi][ni], 0, 0, 0);
        // no trailing barrier: next iter writes the OTHER buffer; writes two
        // iters ahead are ordered after this iter's reads by the next barrier's
        // preceding lgkmcnt(0).
    }

    // --- epilogue: bias + store rows of real batches ---
#pragma unroll
    for (int mi = 0; mi < 4; ++mi) {
        const int slot = wm * 2 + (mi >> 1);
        if (slot < nb) {
            const int batch = rec[2 + slot];
            const int rbase = wm * 64 + mi * 16 + kb * 4;
#pragma unroll
            for (int j = 0; j < 4; ++j) {
                const int trow = (rbase + j) & 31;
                float* orow = out + (size_t)(batch * TT + trow) * DH + n0 + wn * 64;
#pragma unroll
                for (int ni = 0; ni < 4; ++ni)
                    orow[ni * 16 + fl] = acc[mi][ni][j] + bv[ni];
            }
        }
    }
}

extern "C" void kernel_launch(void* const* d_in, const int* in_sizes, int n_in,
                              void* d_out, int out_size, void* d_ws, size_t ws_size,
                              hipStream_t stream) {
    const float* x       = (const float*)d_in[0];
    const int*   cat_ids = (const int*)d_in[1];
    const float* W       = (const float*)d_in[2];
    const float* bias    = (const float*)d_in[3];
    float*       out     = (float*)d_out;
    int*         recs    = (int*)d_ws;

    hipLaunchKernelGGL(cat_setup_kernel, dim3(1), dim3(256), 0, stream,
                       cat_ids, recs);
    hipLaunchKernelGGL(cat_gemm_kernel, dim3(MAXREC * NTILES), dim3(256), 0, stream,
                       x, W, bias, recs, out);
}